// Round 6
// baseline (376.359 us; speedup 1.0000x reference)
//
#include <hip/hip_runtime.h>
#include <hip/hip_bf16.h>
#include <hip/hip_fp16.h>

// GCN 2-layer forward on gfx950 — CSR radix partition + fp16 gather operands.
//
//   layer 1: xh = fp16(dinv ⊙ x);  t[d] = dinv[d]*(xh[d] + Σ xh[s])  (fp32 acc)
//            h = relu(t W1 + b1)                                      (fp32 GEMM)
//   layer 2: yh = fp16(dinv ⊙ (h W2));  out[d] = dinv[d]*(yh[d] + Σ yh[s]) + b2
//
// R6: gathers were L2-miss-byte bound (R5: gather1 110us, FETCH 196MB vs
// 25.6MB working set). fp16 halves bytes/row; dinv pre-scaling removes the
// per-edge dinv load+shfl. xh aliases dead tmp space (in h), yh aliases t.

static constexpr int FIN = 64;
static constexpr int HID = 128;
static constexpr int CLS = 40;
static constexpr int NB_MAX = 392;   // buckets of 256 nodes; N <= 100352
static constexpr int NWG_P = 256;    // partition workgroups

// ---------------- CSR build: radix partition by dst>>8 ----------------

__global__ __launch_bounds__(1024) void k_cnt(const int* __restrict__ dst,
                                              int* __restrict__ cntmat,
                                              int E, int NB, int per_wg) {
    __shared__ int lh[NB_MAX];
    const int tid = threadIdx.x, wg = blockIdx.x;
    for (int i = tid; i < NB; i += 1024) lh[i] = 0;
    __syncthreads();
    const int r0 = wg * per_wg, r1 = min(E, r0 + per_wg);
    for (int e = r0 + tid; e < r1; e += 1024)
        atomicAdd(&lh[dst[e] >> 8], 1);
    __syncthreads();
    for (int b = tid; b < NB; b += 1024) cntmat[b * NWG_P + wg] = lh[b];
}

__global__ __launch_bounds__(256) void k_bscan1(int* __restrict__ cntmat,
                                                int* __restrict__ btot) {
    __shared__ int sd[256];
    const int b = blockIdx.x, tid = threadIdx.x;
    int v = cntmat[b * NWG_P + tid];
    sd[tid] = v;
    for (int off = 1; off < 256; off <<= 1) {
        __syncthreads();
        int t = (tid >= off) ? sd[tid - off] : 0;
        __syncthreads();
        sd[tid] += t;
    }
    __syncthreads();
    cntmat[b * NWG_P + tid] = sd[tid] - v;
    if (tid == 255) btot[b] = sd[255];
}

__global__ __launch_bounds__(512) void k_bscan2(const int* __restrict__ btot,
                                                int* __restrict__ bbase,
                                                int NB, int E) {
    __shared__ int sd[512];
    const int tid = threadIdx.x;
    int v = (tid < NB) ? btot[tid] : 0;
    sd[tid] = v;
    for (int off = 1; off < 512; off <<= 1) {
        __syncthreads();
        int t = (tid >= off) ? sd[tid - off] : 0;
        __syncthreads();
        sd[tid] += t;
    }
    __syncthreads();
    if (tid < NB) bbase[tid] = sd[tid] - v;
    if (tid == 0) bbase[NB] = E;
}

__global__ __launch_bounds__(1024) void k_scat(const int* __restrict__ ei,
                                               const int* __restrict__ cntmat,
                                               const int* __restrict__ bbase,
                                               unsigned* __restrict__ tmp,
                                               int E, int NB, int per_wg) {
    __shared__ int lcur[NB_MAX];
    const int tid = threadIdx.x, wg = blockIdx.x;
    for (int b = tid; b < NB; b += 1024)
        lcur[b] = cntmat[b * NWG_P + wg] + bbase[b];
    __syncthreads();
    const int r0 = wg * per_wg, r1 = min(E, r0 + per_wg);
    for (int e = r0 + tid; e < r1; e += 1024) {
        int s = ei[e], d = ei[E + e];
        int b = d >> 8;
        int pos = atomicAdd(&lcur[b], 1);
        tmp[pos] = ((unsigned)(d & 255) << 24) | (unsigned)s;
    }
}

__global__ __launch_bounds__(256) void k_p2(const unsigned* __restrict__ tmp,
                                            const int* __restrict__ bbase,
                                            int* __restrict__ rstart,
                                            int* __restrict__ cnt,
                                            float* __restrict__ dinv,
                                            int* __restrict__ ssrc, int N) {
    __shared__ int nh[256];
    __shared__ int sd[256];
    __shared__ int curs[256];
    const int tid = threadIdx.x;
    const int b = blockIdx.x;
    const int node0 = b << 8;
    const int e0 = bbase[b], e1 = bbase[b + 1];
    nh[tid] = 0;
    __syncthreads();
    for (int e = e0 + tid; e < e1; e += 256)
        atomicAdd(&nh[tmp[e] >> 24], 1);
    __syncthreads();
    int v = nh[tid];
    sd[tid] = v;
    for (int off = 1; off < 256; off <<= 1) {
        __syncthreads();
        int t = (tid >= off) ? sd[tid - off] : 0;
        __syncthreads();
        sd[tid] += t;
    }
    __syncthreads();
    int rs = e0 + sd[tid] - v;
    int node = node0 + tid;
    if (node < N) {
        rstart[node] = rs;
        cnt[node] = v;
        dinv[node] = rsqrtf((float)v + 1.0f);
    }
    curs[tid] = rs;
    __syncthreads();
    for (int e = e0 + tid; e < e1; e += 256) {
        unsigned p = tmp[e];
        int slot = atomicAdd(&curs[p >> 24], 1);
        ssrc[slot] = (int)(p & 0xFFFFFFu);
    }
}

// xh = fp16(dinv ⊙ x): one thread per 2 elements (half2 store).
__global__ __launch_bounds__(256) void k_prescale(const float* __restrict__ x,
                                                  const float* __restrict__ dinv,
                                                  __half* __restrict__ xh, int N) {
    int idx = blockIdx.x * 256 + threadIdx.x;   // over N*32
    if (idx >= N * 32) return;
    int i = idx >> 5;
    float dv = dinv[i];
    float2 v = *(const float2*)&x[(size_t)idx * 2];
    __half2 o;
    o.x = __float2half(dv * v.x);
    o.y = __float2half(dv * v.y);
    *(__half2*)&xh[(size_t)idx * 2] = o;
}

// ---------------- gather-aggregate (fp16 in, fp32 out) ----------------
// out[d] = dinv[d] * ( X[d] + sum_s X[s] ) (+bias)   [X rows pre-scaled fp16]

template <int F, bool BIAS>
__global__ __launch_bounds__(256) void k_gather_h(const __half* __restrict__ X,
                                                  const float* __restrict__ dinv,
                                                  const int* __restrict__ rstart,
                                                  const int* __restrict__ cnt,
                                                  const int* __restrict__ ssrc,
                                                  const float* __restrict__ bias,
                                                  float* __restrict__ out, int N) {
    int wid = (blockIdx.x * 256 + threadIdx.x) >> 6;
    int lane = threadIdx.x & 63;
    if (wid >= N) return;
    float dv = dinv[wid];
    int st = rstart[wid], c = cnt[wid];
    const bool act = (F == 64) || (lane < F);
    float acc = act ? __half2float(X[(size_t)wid * F + lane]) : 0.f;
    for (int base = 0; base < c; base += 64) {
        int m = min(64, c - base);
        int myS = (lane < m) ? ssrc[st + base + lane] : 0;
#pragma unroll 8
        for (int j = 0; j < m; ++j) {
            int s = __shfl(myS, j);
            if (act) acc += __half2float(X[(size_t)s * F + lane]);
        }
    }
    if (act) {
        float r = dv * acc;
        if (BIAS) r += bias[lane];
        out[(size_t)wid * F + lane] = r;
    }
}

// ---------------- GEMMs ----------------

// h = relu(t @ W1 + b1), 64-row tile, TM=8 x TN=4 (fp32).
__global__ __launch_bounds__(256, 3) void k_gemm1(const float* __restrict__ A,
                                                  const float* __restrict__ W,
                                                  const float* __restrict__ bias,
                                                  float* __restrict__ H, int N) {
    __shared__ float Bs[FIN][132];
    __shared__ float As[64][68];
    const int tid = threadIdx.x;
    {
        const float4* W4 = (const float4*)W;
        for (int i = tid; i < 2048; i += 256) {
            int r = i >> 5, c4 = i & 31;
            *(float4*)&Bs[r][c4 * 4] = W4[i];
        }
    }
    const int row0 = blockIdx.x * 64;
    for (int i = tid; i < 1024; i += 256) {
        int r = i >> 4, c4 = i & 15;
        int gr = row0 + r;
        float4 v = make_float4(0.f, 0.f, 0.f, 0.f);
        if (gr < N) v = *(const float4*)&A[(size_t)gr * FIN + c4 * 4];
        *(float4*)&As[r][c4 * 4] = v;
    }
    __syncthreads();
    const int tc = tid & 31;
    const int tr = tid >> 5;
    float acc[8][4] = {};
#pragma unroll 2
    for (int k = 0; k < FIN; k += 4) {
        float4 bq[4];
#pragma unroll
        for (int kk = 0; kk < 4; ++kk) bq[kk] = *(const float4*)&Bs[k + kk][tc * 4];
#pragma unroll
        for (int i = 0; i < 8; ++i) {
            float4 a = *(const float4*)&As[tr * 8 + i][k];
            float* ac = acc[i];
            ac[0] = fmaf(a.x, bq[0].x, ac[0]); ac[0] = fmaf(a.y, bq[1].x, ac[0]);
            ac[0] = fmaf(a.z, bq[2].x, ac[0]); ac[0] = fmaf(a.w, bq[3].x, ac[0]);
            ac[1] = fmaf(a.x, bq[0].y, ac[1]); ac[1] = fmaf(a.y, bq[1].y, ac[1]);
            ac[1] = fmaf(a.z, bq[2].y, ac[1]); ac[1] = fmaf(a.w, bq[3].y, ac[1]);
            ac[2] = fmaf(a.x, bq[0].z, ac[2]); ac[2] = fmaf(a.y, bq[1].z, ac[2]);
            ac[2] = fmaf(a.z, bq[2].z, ac[2]); ac[2] = fmaf(a.w, bq[3].z, ac[2]);
            ac[3] = fmaf(a.x, bq[0].w, ac[3]); ac[3] = fmaf(a.y, bq[1].w, ac[3]);
            ac[3] = fmaf(a.z, bq[2].w, ac[3]); ac[3] = fmaf(a.w, bq[3].w, ac[3]);
        }
    }
    float4 bv = *(const float4*)&bias[tc * 4];
#pragma unroll
    for (int i = 0; i < 8; ++i) {
        int gr = row0 + tr * 8 + i;
        if (gr < N) {
            float4 v;
            v.x = fmaxf(acc[i][0] + bv.x, 0.f);
            v.y = fmaxf(acc[i][1] + bv.y, 0.f);
            v.z = fmaxf(acc[i][2] + bv.z, 0.f);
            v.w = fmaxf(acc[i][3] + bv.w, 0.f);
            *(float4*)&H[(size_t)gr * HID + tc * 4] = v;
        }
    }
}

// yh = fp16(dinv ⊙ (h @ W2)). A from global (L1 broadcast), LDS = W2 only.
__global__ __launch_bounds__(256, 4) void k_gemm2(const float* __restrict__ H,
                                                  const float* __restrict__ W,
                                                  const float* __restrict__ dinv,
                                                  __half* __restrict__ Yh, int N) {
    __shared__ float Bs[CLS][132];
    const int tid = threadIdx.x;
    for (int i = tid; i < HID * CLS; i += 256) {
        int k = i / CLS, c = i - k * CLS;
        Bs[c][k] = W[i];
    }
    __syncthreads();
    const int row0 = blockIdx.x * 64;
    const int tc = tid & 7;
    const int tr = tid >> 3;
    const int r0 = row0 + tr * 2;
    const int ra = min(r0, N - 1);
    const int rb = min(r0 + 1, N - 1);
    float acc[2][5] = {};
#pragma unroll 2
    for (int k = 0; k < HID; k += 4) {
        float4 b[5];
#pragma unroll
        for (int j = 0; j < 5; ++j) b[j] = *(const float4*)&Bs[tc * 5 + j][k];
        float4 a0 = *(const float4*)&H[(size_t)ra * HID + k];
        float4 a1 = *(const float4*)&H[(size_t)rb * HID + k];
#pragma unroll
        for (int j = 0; j < 5; ++j) {
            acc[0][j] = fmaf(a0.x, b[j].x, fmaf(a0.y, b[j].y,
                        fmaf(a0.z, b[j].z, fmaf(a0.w, b[j].w, acc[0][j]))));
            acc[1][j] = fmaf(a1.x, b[j].x, fmaf(a1.y, b[j].y,
                        fmaf(a1.z, b[j].z, fmaf(a1.w, b[j].w, acc[1][j]))));
        }
    }
    float dva = dinv[ra], dvb = dinv[rb];
#pragma unroll
    for (int i = 0; i < 2; ++i) {
        int gr = r0 + i;
        float dv = (i == 0) ? dva : dvb;
        if (gr < N) {
#pragma unroll
            for (int j = 0; j < 5; ++j)
                Yh[(size_t)gr * CLS + tc * 5 + j] = __float2half(acc[i][j] * dv);
        }
    }
}

// ---------------- launch ----------------

extern "C" void kernel_launch(void* const* d_in, const int* in_sizes, int n_in,
                              void* d_out, int out_size, void* d_ws, size_t ws_size,
                              hipStream_t stream) {
    const float* x  = (const float*)d_in[0];
    const int*   ei = (const int*)d_in[1];   // [2][E]
    const float* W1 = (const float*)d_in[2];
    const float* b1 = (const float*)d_in[3];
    const float* W2 = (const float*)d_in[4];
    const float* b2 = (const float*)d_in[5];
    float* out = (float*)d_out;

    const int N = in_sizes[0] / FIN;
    const int E = in_sizes[1] / 2;
    const int NB = (N + 255) >> 8;
    const int per_wg = (E + NWG_P - 1) / NWG_P;

    float* dinv   = (float*)d_ws;                  // N
    float* t      = dinv + N;                      // N*FIN f32 (later yh fp16)
    float* h      = t + (size_t)N * FIN;           // N*HID f32 (tmp/xh overlap)
    int* cnt      = (int*)(h + (size_t)N * HID);   // N
    int* rstart   = cnt + N;                       // N
    int* ssrc     = rstart + N;                    // E
    int* cntmat   = ssrc + E;                      // NB_MAX*NWG_P
    int* btot     = cntmat + NB_MAX * NWG_P;       // NB_MAX
    int* bbase    = btot + NB_MAX;                 // NB_MAX+1
    unsigned* tmp = (unsigned*)h;                  // E words (dead after p2)
    __half* xh    = (__half*)h;                    // N*FIN halves (dead before gemm1)
    __half* yh    = (__half*)t;                    // N*CLS halves (after gemm1)

    dim3 blk(256);
    // CSR build: radix partition by dst
    hipLaunchKernelGGL(k_cnt,    dim3(NWG_P), dim3(1024), 0, stream, ei + E, cntmat, E, NB, per_wg);
    hipLaunchKernelGGL(k_bscan1, dim3(NB), blk, 0, stream, cntmat, btot);
    hipLaunchKernelGGL(k_bscan2, dim3(1), dim3(512), 0, stream, btot, bbase, NB, E);
    hipLaunchKernelGGL(k_scat,   dim3(NWG_P), dim3(1024), 0, stream, ei, cntmat, bbase, tmp, E, NB, per_wg);
    hipLaunchKernelGGL(k_p2,     dim3(NB), blk, 0, stream, tmp, bbase, rstart, cnt, dinv, ssrc, N);
    // layer 1: prescale -> fp16 gather -> fp32 GEMM+bias+relu
    hipLaunchKernelGGL(k_prescale, dim3((N * 32 + 255) / 256), blk, 0, stream, x, dinv, xh, N);
    hipLaunchKernelGGL((k_gather_h<FIN, false>), dim3((N + 3) / 4), blk, 0, stream,
                       xh, dinv, rstart, cnt, ssrc, (const float*)nullptr, t, N);
    hipLaunchKernelGGL(k_gemm1, dim3((N + 63) / 64), blk, 0, stream, t, W1, b1, h, N);
    // layer 2: GEMM (scaled fp16 rows) -> fp16 gather + bias
    hipLaunchKernelGGL(k_gemm2, dim3((N + 63) / 64), blk, 0, stream, h, W2, dinv, yh, N);
    hipLaunchKernelGGL((k_gather_h<CLS, true>), dim3((N + 3) / 4), blk, 0, stream,
                       yh, dinv, rstart, cnt, ssrc, b2, out, N);
}

// Round 7
// 269.561 us; speedup vs baseline: 1.3962x; 1.3962x over previous
//
#include <hip/hip_runtime.h>
#include <hip/hip_bf16.h>
#include <hip/hip_fp16.h>

// GCN 2-layer forward on gfx950 — CSR radix partition + 16B/lane packed gather.
//
//   layer 1: xh = fp16(dinv ⊙ x);  t[d] = dinv[d]*(xh[d] + Σ xh[s])  (fp32 acc)
//            h = relu(t W1 + b1)                                      (fp32 GEMM)
//   layer 2: yh = fp16(dinv ⊙ (h W2)) padded to 64; out = dinv⊙(Σ) + b2
//
// R7: gathers were per-load-instruction bound (R6: fp16 halved FETCH 196->96MB
// but time flat at 103us => ~40 cyc/wave-load pipe cost dominates). Repack:
// lane loads int4 (8 fp16 feats), 8 lanes/row, one dwordx4 covers 8 edges
// (1KiB/instr, the 16B/lane sweet spot). 17 loads/row -> 3. Cross-group
// reduction via shfl_xor(8/16/32). yh padded 40->64 halves to share the path.

static constexpr int FIN = 64;
static constexpr int HID = 128;
static constexpr int CLS = 40;
static constexpr int NB_MAX = 392;   // buckets of 256 nodes; N <= 100352
static constexpr int NWG_P = 256;    // partition workgroups

// ---------------- CSR build: radix partition by dst>>8 ----------------

__global__ __launch_bounds__(1024) void k_cnt(const int* __restrict__ dst,
                                              int* __restrict__ cntmat,
                                              int E, int NB, int per_wg) {
    __shared__ int lh[NB_MAX];
    const int tid = threadIdx.x, wg = blockIdx.x;
    for (int i = tid; i < NB; i += 1024) lh[i] = 0;
    __syncthreads();
    const int r0 = wg * per_wg, r1 = min(E, r0 + per_wg);
    for (int e = r0 + tid; e < r1; e += 1024)
        atomicAdd(&lh[dst[e] >> 8], 1);
    __syncthreads();
    for (int b = tid; b < NB; b += 1024) cntmat[b * NWG_P + wg] = lh[b];
}

__global__ __launch_bounds__(256) void k_bscan1(int* __restrict__ cntmat,
                                                int* __restrict__ btot) {
    __shared__ int sd[256];
    const int b = blockIdx.x, tid = threadIdx.x;
    int v = cntmat[b * NWG_P + tid];
    sd[tid] = v;
    for (int off = 1; off < 256; off <<= 1) {
        __syncthreads();
        int t = (tid >= off) ? sd[tid - off] : 0;
        __syncthreads();
        sd[tid] += t;
    }
    __syncthreads();
    cntmat[b * NWG_P + tid] = sd[tid] - v;
    if (tid == 255) btot[b] = sd[255];
}

__global__ __launch_bounds__(512) void k_bscan2(const int* __restrict__ btot,
                                                int* __restrict__ bbase,
                                                int NB, int E) {
    __shared__ int sd[512];
    const int tid = threadIdx.x;
    int v = (tid < NB) ? btot[tid] : 0;
    sd[tid] = v;
    for (int off = 1; off < 512; off <<= 1) {
        __syncthreads();
        int t = (tid >= off) ? sd[tid - off] : 0;
        __syncthreads();
        sd[tid] += t;
    }
    __syncthreads();
    if (tid < NB) bbase[tid] = sd[tid] - v;
    if (tid == 0) bbase[NB] = E;
}

__global__ __launch_bounds__(1024) void k_scat(const int* __restrict__ ei,
                                               const int* __restrict__ cntmat,
                                               const int* __restrict__ bbase,
                                               unsigned* __restrict__ tmp,
                                               int E, int NB, int per_wg) {
    __shared__ int lcur[NB_MAX];
    const int tid = threadIdx.x, wg = blockIdx.x;
    for (int b = tid; b < NB; b += 1024)
        lcur[b] = cntmat[b * NWG_P + wg] + bbase[b];
    __syncthreads();
    const int r0 = wg * per_wg, r1 = min(E, r0 + per_wg);
    for (int e = r0 + tid; e < r1; e += 1024) {
        int s = ei[e], d = ei[E + e];
        int b = d >> 8;
        int pos = atomicAdd(&lcur[b], 1);
        tmp[pos] = ((unsigned)(d & 255) << 24) | (unsigned)s;
    }
}

__global__ __launch_bounds__(256) void k_p2(const unsigned* __restrict__ tmp,
                                            const int* __restrict__ bbase,
                                            int* __restrict__ rstart,
                                            int* __restrict__ cnt,
                                            float* __restrict__ dinv,
                                            int* __restrict__ ssrc, int N) {
    __shared__ int nh[256];
    __shared__ int sd[256];
    __shared__ int curs[256];
    const int tid = threadIdx.x;
    const int b = blockIdx.x;
    const int node0 = b << 8;
    const int e0 = bbase[b], e1 = bbase[b + 1];
    nh[tid] = 0;
    __syncthreads();
    for (int e = e0 + tid; e < e1; e += 256)
        atomicAdd(&nh[tmp[e] >> 24], 1);
    __syncthreads();
    int v = nh[tid];
    sd[tid] = v;
    for (int off = 1; off < 256; off <<= 1) {
        __syncthreads();
        int t = (tid >= off) ? sd[tid - off] : 0;
        __syncthreads();
        sd[tid] += t;
    }
    __syncthreads();
    int rs = e0 + sd[tid] - v;
    int node = node0 + tid;
    if (node < N) {
        rstart[node] = rs;
        cnt[node] = v;
        dinv[node] = rsqrtf((float)v + 1.0f);
    }
    curs[tid] = rs;
    __syncthreads();
    for (int e = e0 + tid; e < e1; e += 256) {
        unsigned p = tmp[e];
        int slot = atomicAdd(&curs[p >> 24], 1);
        ssrc[slot] = (int)(p & 0xFFFFFFu);
    }
}

// xh = fp16(dinv ⊙ x): one thread per 2 elements (half2 store).
__global__ __launch_bounds__(256) void k_prescale(const float* __restrict__ x,
                                                  const float* __restrict__ dinv,
                                                  __half* __restrict__ xh, int N) {
    int idx = blockIdx.x * 256 + threadIdx.x;   // over N*32
    if (idx >= N * 32) return;
    int i = idx >> 5;
    float dv = dinv[i];
    float2 v = *(const float2*)&x[(size_t)idx * 2];
    __half2 o;
    o.x = __float2half(dv * v.x);
    o.y = __float2half(dv * v.y);
    *(__half2*)&xh[(size_t)idx * 2] = o;
}

// ---------------- packed gather-aggregate ----------------
// X: fp16 rows of 64 halves (128B). One wave per dst row. Lane l handles
// edge-slot (l>>3), 16B chunk (l&7). One dwordx4 covers 8 edge rows.
// Virtual edge list: slot 0 = self row, slots 1..c = ssrc.
// out[d][f<FOUT] = dinv[d] * sum + bias[f]

template <int FOUT, bool BIAS>
__global__ __launch_bounds__(256) void k_gather16(const __half* __restrict__ X,
                                                  const float* __restrict__ dinv,
                                                  const int* __restrict__ rstart,
                                                  const int* __restrict__ cnt,
                                                  const int* __restrict__ ssrc,
                                                  const float* __restrict__ bias,
                                                  float* __restrict__ out, int N) {
    const int wid = (blockIdx.x * 256 + threadIdx.x) >> 6;
    const int lane = threadIdx.x & 63;
    if (wid >= N) return;
    const int grp = lane >> 3, sub = lane & 7;
    const float dv = dinv[wid];
    const int st = rstart[wid], c = cnt[wid];
    const int total = c + 1;
    float acc[8] = {0.f, 0.f, 0.f, 0.f, 0.f, 0.f, 0.f, 0.f};
    for (int base = 0; base < total; base += 64) {
        const int m = min(64, total - base);
        const int eidx = base + lane;
        int myS = wid;                       // slot 0 = self
        if (eidx > 0 && eidx < total) myS = ssrc[st + eidx - 1];
        const int gmax = (m + 7) >> 3;
#pragma unroll 4
        for (int g = 0; g < gmax; ++g) {
            const int slot = g * 8 + grp;
            const int s = __shfl(myS, min(slot, m - 1));
            const float w = (slot < m) ? 1.f : 0.f;
            const int4 v = *(const int4*)(X + ((size_t)s << 6) + (sub << 3));
            const __half2 h0 = *(const __half2*)&v.x;
            const __half2 h1 = *(const __half2*)&v.y;
            const __half2 h2 = *(const __half2*)&v.z;
            const __half2 h3 = *(const __half2*)&v.w;
            acc[0] = fmaf(w, __low2float(h0),  acc[0]);
            acc[1] = fmaf(w, __high2float(h0), acc[1]);
            acc[2] = fmaf(w, __low2float(h1),  acc[2]);
            acc[3] = fmaf(w, __high2float(h1), acc[3]);
            acc[4] = fmaf(w, __low2float(h2),  acc[4]);
            acc[5] = fmaf(w, __high2float(h2), acc[5]);
            acc[6] = fmaf(w, __low2float(h3),  acc[6]);
            acc[7] = fmaf(w, __high2float(h3), acc[7]);
        }
    }
#pragma unroll
    for (int k = 0; k < 8; ++k) {
        acc[k] += __shfl_xor(acc[k], 8);
        acc[k] += __shfl_xor(acc[k], 16);
        acc[k] += __shfl_xor(acc[k], 32);
    }
    // lanes 0-7 store feats [8*sub, +4); lanes 8-15 store [8*sub+4, +4)
    const int f0 = sub * 8 + (grp & 1) * 4;
    if (grp < 2 && f0 < FOUT) {
        const int k0 = (grp & 1) * 4;
        float4 o = make_float4(acc[k0] * dv, acc[k0 + 1] * dv,
                               acc[k0 + 2] * dv, acc[k0 + 3] * dv);
        if (BIAS) {
            float4 bb = *(const float4*)&bias[f0];
            o.x += bb.x; o.y += bb.y; o.z += bb.z; o.w += bb.w;
        }
        *(float4*)&out[(size_t)wid * FOUT + f0] = o;
    }
}

// ---------------- GEMMs ----------------

// h = relu(t @ W1 + b1), 64-row tile, TM=8 x TN=4 (fp32).
__global__ __launch_bounds__(256, 3) void k_gemm1(const float* __restrict__ A,
                                                  const float* __restrict__ W,
                                                  const float* __restrict__ bias,
                                                  float* __restrict__ H, int N) {
    __shared__ float Bs[FIN][132];
    __shared__ float As[64][68];
    const int tid = threadIdx.x;
    {
        const float4* W4 = (const float4*)W;
        for (int i = tid; i < 2048; i += 256) {
            int r = i >> 5, c4 = i & 31;
            *(float4*)&Bs[r][c4 * 4] = W4[i];
        }
    }
    const int row0 = blockIdx.x * 64;
    for (int i = tid; i < 1024; i += 256) {
        int r = i >> 4, c4 = i & 15;
        int gr = row0 + r;
        float4 v = make_float4(0.f, 0.f, 0.f, 0.f);
        if (gr < N) v = *(const float4*)&A[(size_t)gr * FIN + c4 * 4];
        *(float4*)&As[r][c4 * 4] = v;
    }
    __syncthreads();
    const int tc = tid & 31;
    const int tr = tid >> 5;
    float acc[8][4] = {};
#pragma unroll 2
    for (int k = 0; k < FIN; k += 4) {
        float4 bq[4];
#pragma unroll
        for (int kk = 0; kk < 4; ++kk) bq[kk] = *(const float4*)&Bs[k + kk][tc * 4];
#pragma unroll
        for (int i = 0; i < 8; ++i) {
            float4 a = *(const float4*)&As[tr * 8 + i][k];
            float* ac = acc[i];
            ac[0] = fmaf(a.x, bq[0].x, ac[0]); ac[0] = fmaf(a.y, bq[1].x, ac[0]);
            ac[0] = fmaf(a.z, bq[2].x, ac[0]); ac[0] = fmaf(a.w, bq[3].x, ac[0]);
            ac[1] = fmaf(a.x, bq[0].y, ac[1]); ac[1] = fmaf(a.y, bq[1].y, ac[1]);
            ac[1] = fmaf(a.z, bq[2].y, ac[1]); ac[1] = fmaf(a.w, bq[3].y, ac[1]);
            ac[2] = fmaf(a.x, bq[0].z, ac[2]); ac[2] = fmaf(a.y, bq[1].z, ac[2]);
            ac[2] = fmaf(a.z, bq[2].z, ac[2]); ac[2] = fmaf(a.w, bq[3].z, ac[2]);
            ac[3] = fmaf(a.x, bq[0].w, ac[3]); ac[3] = fmaf(a.y, bq[1].w, ac[3]);
            ac[3] = fmaf(a.z, bq[2].w, ac[3]); ac[3] = fmaf(a.w, bq[3].w, ac[3]);
        }
    }
    float4 bv = *(const float4*)&bias[tc * 4];
#pragma unroll
    for (int i = 0; i < 8; ++i) {
        int gr = row0 + tr * 8 + i;
        if (gr < N) {
            float4 v;
            v.x = fmaxf(acc[i][0] + bv.x, 0.f);
            v.y = fmaxf(acc[i][1] + bv.y, 0.f);
            v.z = fmaxf(acc[i][2] + bv.z, 0.f);
            v.w = fmaxf(acc[i][3] + bv.w, 0.f);
            *(float4*)&H[(size_t)gr * HID + tc * 4] = v;
        }
    }
}

// yh = fp16(dinv ⊙ (h @ W2)) into padded rows of 64 halves (pad zeroed).
__global__ __launch_bounds__(256, 4) void k_gemm2(const float* __restrict__ H,
                                                  const float* __restrict__ W,
                                                  const float* __restrict__ dinv,
                                                  __half* __restrict__ Yh, int N) {
    __shared__ float Bs[CLS][132];
    const int tid = threadIdx.x;
    for (int i = tid; i < HID * CLS; i += 256) {
        int k = i / CLS, c = i - k * CLS;
        Bs[c][k] = W[i];
    }
    __syncthreads();
    const int row0 = blockIdx.x * 64;
    const int tc = tid & 7;
    const int tr = tid >> 3;
    const int r0 = row0 + tr * 2;
    const int ra = min(r0, N - 1);
    const int rb = min(r0 + 1, N - 1);
    float acc[2][5] = {};
#pragma unroll 2
    for (int k = 0; k < HID; k += 4) {
        float4 b[5];
#pragma unroll
        for (int j = 0; j < 5; ++j) b[j] = *(const float4*)&Bs[tc * 5 + j][k];
        float4 a0 = *(const float4*)&H[(size_t)ra * HID + k];
        float4 a1 = *(const float4*)&H[(size_t)rb * HID + k];
#pragma unroll
        for (int j = 0; j < 5; ++j) {
            acc[0][j] = fmaf(a0.x, b[j].x, fmaf(a0.y, b[j].y,
                        fmaf(a0.z, b[j].z, fmaf(a0.w, b[j].w, acc[0][j]))));
            acc[1][j] = fmaf(a1.x, b[j].x, fmaf(a1.y, b[j].y,
                        fmaf(a1.z, b[j].z, fmaf(a1.w, b[j].w, acc[1][j]))));
        }
    }
    float dva = dinv[ra], dvb = dinv[rb];
#pragma unroll
    for (int i = 0; i < 2; ++i) {
        int gr = r0 + i;
        float dv = (i == 0) ? dva : dvb;
        if (gr < N) {
#pragma unroll
            for (int j = 0; j < 5; ++j)
                Yh[(size_t)gr * 64 + tc * 5 + j] = __float2half(acc[i][j] * dv);
        }
    }
    // zero the pad: halves 40..63 of each row = half2 slots 20..31
    const __half2 z = __float2half2_rn(0.f);
    for (int i = tid; i < 64 * 12; i += 256) {
        int r = row0 + i / 12, c2 = 20 + i % 12;
        if (r < N) ((__half2*)&Yh[(size_t)r * 64])[c2] = z;
    }
}

// ---------------- launch ----------------

extern "C" void kernel_launch(void* const* d_in, const int* in_sizes, int n_in,
                              void* d_out, int out_size, void* d_ws, size_t ws_size,
                              hipStream_t stream) {
    const float* x  = (const float*)d_in[0];
    const int*   ei = (const int*)d_in[1];   // [2][E]
    const float* W1 = (const float*)d_in[2];
    const float* b1 = (const float*)d_in[3];
    const float* W2 = (const float*)d_in[4];
    const float* b2 = (const float*)d_in[5];
    float* out = (float*)d_out;

    const int N = in_sizes[0] / FIN;
    const int E = in_sizes[1] / 2;
    const int NB = (N + 255) >> 8;
    const int per_wg = (E + NWG_P - 1) / NWG_P;

    float* dinv   = (float*)d_ws;                  // N
    float* t      = dinv + N;                      // N*FIN f32 (later yh fp16 padded)
    float* h      = t + (size_t)N * FIN;           // N*HID f32 (tmp/xh overlap)
    int* cnt      = (int*)(h + (size_t)N * HID);   // N
    int* rstart   = cnt + N;                       // N
    int* ssrc     = rstart + N;                    // E
    int* cntmat   = ssrc + E;                      // NB_MAX*NWG_P
    int* btot     = cntmat + NB_MAX * NWG_P;       // NB_MAX
    int* bbase    = btot + NB_MAX;                 // NB_MAX+1
    unsigned* tmp = (unsigned*)h;                  // E words (dead after p2)
    __half* xh    = (__half*)h;                    // N*64 halves (dead before gemm1)
    __half* yh    = (__half*)t;                    // N*64 halves (after gemm1)

    dim3 blk(256);
    // CSR build: radix partition by dst
    hipLaunchKernelGGL(k_cnt,    dim3(NWG_P), dim3(1024), 0, stream, ei + E, cntmat, E, NB, per_wg);
    hipLaunchKernelGGL(k_bscan1, dim3(NB), blk, 0, stream, cntmat, btot);
    hipLaunchKernelGGL(k_bscan2, dim3(1), dim3(512), 0, stream, btot, bbase, NB, E);
    hipLaunchKernelGGL(k_scat,   dim3(NWG_P), dim3(1024), 0, stream, ei, cntmat, bbase, tmp, E, NB, per_wg);
    hipLaunchKernelGGL(k_p2,     dim3(NB), blk, 0, stream, tmp, bbase, rstart, cnt, dinv, ssrc, N);
    // layer 1: prescale -> packed fp16 gather -> fp32 GEMM+bias+relu
    hipLaunchKernelGGL(k_prescale, dim3((N * 32 + 255) / 256), blk, 0, stream, x, dinv, xh, N);
    hipLaunchKernelGGL((k_gather16<FIN, false>), dim3((N + 3) / 4), blk, 0, stream,
                       xh, dinv, rstart, cnt, ssrc, (const float*)nullptr, t, N);
    hipLaunchKernelGGL(k_gemm1, dim3((N + 63) / 64), blk, 0, stream, t, W1, b1, h, N);
    // layer 2: GEMM (scaled fp16 rows, padded) -> packed fp16 gather + bias
    hipLaunchKernelGGL(k_gemm2, dim3((N + 63) / 64), blk, 0, stream, h, W2, dinv, yh, N);
    hipLaunchKernelGGL((k_gather16<CLS, true>), dim3((N + 3) / 4), blk, 0, stream,
                       yh, dinv, rstart, cnt, ssrc, b2, out, N);
}